// Round 13
// baseline (321.592 us; speedup 1.0000x reference)
//
#include <hip/hip_runtime.h>

#define BS 256

// ---------------- bf16 helpers ----------------
__device__ __forceinline__ unsigned short f2bf(float f) {
    unsigned x = __float_as_uint(f);
    return (unsigned short)((x + 0x7fffu + ((x >> 16) & 1u)) >> 16);
}
__device__ __forceinline__ void unpack8(uint4 v, float* d) {
    d[0] = __uint_as_float(v.x << 16); d[1] = __uint_as_float(v.x & 0xFFFF0000u);
    d[2] = __uint_as_float(v.y << 16); d[3] = __uint_as_float(v.y & 0xFFFF0000u);
    d[4] = __uint_as_float(v.z << 16); d[5] = __uint_as_float(v.z & 0xFFFF0000u);
    d[6] = __uint_as_float(v.w << 16); d[7] = __uint_as_float(v.w & 0xFFFF0000u);
}
__device__ __forceinline__ uint4 pack8bf(const float* r) {
    unsigned w[4];
#pragma unroll
    for (int j = 0; j < 4; j++)
        w[j] = (unsigned)f2bf(r[2 * j]) | ((unsigned)f2bf(r[2 * j + 1]) << 16);
    return make_uint4(w[0], w[1], w[2], w[3]);
}

// ---- node prep: x16 = relu(relu(x_feat @ lpW + lpb) @ tW + tb) ----
__global__ void prep_kernel(const float* __restrict__ xf,
                            const float* __restrict__ W1, const float* __restrict__ b1,
                            const float* __restrict__ W2, const float* __restrict__ b2,
                            float* __restrict__ x16, int N)
{
    int n = blockIdx.x * blockDim.x + threadIdx.x;
    bool valid = n < N;
    int nn = valid ? n : 0;
    float a[24];
#pragma unroll
    for (int i = 0; i < 24; i += 4)
        *(float4*)(a + i) = *(const float4*)(xf + (size_t)nn * 24 + i);
    float h[32];
#pragma unroll
    for (int j = 0; j < 32; j++) {
        float s = b1[j];
#pragma unroll
        for (int i = 0; i < 24; i++) s = fmaf(a[i], W1[i * 32 + j], s);
        h[j] = fmaxf(s, 0.f);
    }
    if (!valid) return;
#pragma unroll
    for (int j = 0; j < 16; j++) {
        float s = b2[j];
#pragma unroll
        for (int i = 0; i < 32; i++) s = fmaf(h[i], W2[i * 16 + j], s);
        x16[(size_t)n * 16 + j] = fmaxf(s, 0.f);
    }
}

// ---- counting pass: 4 edges/thread, 8 atomics in flight before any wait ----
__global__ void degjj_kernel(const int* __restrict__ srcA, const int* __restrict__ dstA,
                             int* __restrict__ cntS, int* __restrict__ cntD,
                             int* __restrict__ jS, int* __restrict__ jD, int E)
{
    int base = blockIdx.x * (BS * 4) + threadIdx.x;
    int e0 = base, e1 = base + BS, e2 = base + 2 * BS, e3 = base + 3 * BS;
    bool v0 = e0 < E, v1 = e1 < E, v2 = e2 < E, v3 = e3 < E;
    int s0 = 0, s1 = 0, s2 = 0, s3 = 0, d0 = 0, d1 = 0, d2 = 0, d3 = 0;
    if (v0) { s0 = srcA[e0]; d0 = dstA[e0]; }
    if (v1) { s1 = srcA[e1]; d1 = dstA[e1]; }
    if (v2) { s2 = srcA[e2]; d2 = dstA[e2]; }
    if (v3) { s3 = srcA[e3]; d3 = dstA[e3]; }
    int a0 = 0, a1 = 0, a2 = 0, a3 = 0, b0 = 0, b1 = 0, b2 = 0, b3 = 0;
    if (v0) { a0 = atomicAdd(&cntS[s0], 1); b0 = atomicAdd(&cntD[d0], 1); }
    if (v1) { a1 = atomicAdd(&cntS[s1], 1); b1 = atomicAdd(&cntD[d1], 1); }
    if (v2) { a2 = atomicAdd(&cntS[s2], 1); b2 = atomicAdd(&cntD[d2], 1); }
    if (v3) { a3 = atomicAdd(&cntS[s3], 1); b3 = atomicAdd(&cntD[d3], 1); }
    if (v0) { jS[e0] = a0; jD[e0] = b0; }
    if (v1) { jS[e1] = a1; jD[e1] = b1; }
    if (v2) { jS[e2] = a2; jD[e2] = b2; }
    if (v3) { jS[e3] = a3; jD[e3] = b3; }
}

// wave-scan offsets: 1 cursor atomic per wave
__global__ void offsets2_kernel(const int* __restrict__ cntS, const int* __restrict__ cntD,
                                int* __restrict__ offsS, int* __restrict__ offsD,
                                int* __restrict__ cursS, int* __restrict__ cursD, int N)
{
    int n = blockIdx.x * blockDim.x + threadIdx.x;
    int lane = threadIdx.x & 63;
    bool valid = n < N;
    int dS = valid ? cntS[n] : 0;
    int dD = valid ? cntD[n] : 0;
    int sS = dS, sD = dD;
#pragma unroll
    for (int o = 1; o < 64; o <<= 1) {
        int tS = __shfl_up(sS, o);
        int tD = __shfl_up(sD, o);
        if (lane >= o) { sS += tS; sD += tD; }
    }
    int totS = __shfl(sS, 63);
    int totD = __shfl(sD, 63);
    int baseS = 0, baseD = 0;
    if (lane == 63) {
        baseS = atomicAdd(cursS, totS);
        baseD = atomicAdd(cursD, totD);
    }
    baseS = __shfl(baseS, 63);
    baseD = __shfl(baseD, 63);
    if (valid) {
        offsS[n] = baseS + sS - dS;
        offsD[n] = baseD + sD - dD;
    }
}

// ---- fused fill + edge trunk: coalesced eattr, no atomics ----
__global__ __launch_bounds__(BS) void er_fill_kernel(
    const int* __restrict__ srcA, const int* __restrict__ dstA,
    const int* __restrict__ jS, const int* __restrict__ jD,
    const int* __restrict__ offsS, const int* __restrict__ offsD,
    const float* __restrict__ eattr,
    const float* __restrict__ eW1, const float* __restrict__ eb1,
    const float* __restrict__ eW2, const float* __restrict__ eb2,
    uint2* __restrict__ spq, unsigned short* __restrict__ er_s, int E)
{
    int e = blockIdx.x * BS + threadIdx.x;
    if (e >= E) return;
    int s = srcA[e], d = dstA[e];
    int p = offsS[s] + jS[e];
    int q = offsD[d] + jD[e];
    spq[p] = make_uint2((unsigned)s, (unsigned)q);

    float ea[16];
#pragma unroll
    for (int i = 0; i < 16; i += 4)
        *(float4*)(ea + i) = *(const float4*)(eattr + (size_t)e * 16 + i);
    float h[32];
#pragma unroll
    for (int j = 0; j < 32; j++) {
        float t = eb1[j];
#pragma unroll
        for (int i = 0; i < 16; i++) t = fmaf(ea[i], eW1[i * 32 + j], t);
        h[j] = fmaxf(t, 0.f);
    }
    float er[16];
#pragma unroll
    for (int j = 0; j < 16; j++) {
        float t = eb2[j];
#pragma unroll
        for (int i = 0; i < 32; i++) t = fmaf(h[i], eW2[i * 16 + j], t);
        er[j] = 1.f / (1.f + __expf(-t));
    }
    uint4* qo = (uint4*)(er_s + (size_t)p * 16);
    qo[0] = pack8bf(er);
    qo[1] = pack8bf(er + 8);
}

// ---- per-(node-pair, k, a) Y precompute ----
// Y layout [17][3][N][8] bf16; root layout [3][N][8] fp32.
// blockIdx.y = k (0..17), blockIdx.z = a (0..2). k==17 -> root slice a.
template <int IN>
__global__ __launch_bounds__(BS) void ynode_kernel(const float* __restrict__ x,
                                                   const float* __restrict__ W,   // [3][16][IN*8]
                                                   const float* __restrict__ B,   // [3][IN*8]
                                                   const float* __restrict__ RW,  // [3][IN][8]
                                                   const float* __restrict__ RB,  // [3][8]
                                                   unsigned short* __restrict__ Y,
                                                   float* __restrict__ root, int N)
{
    __shared__ float4 w4[IN * 2];
    int t = threadIdx.x;
    int k = blockIdx.y;            // 0..17, block-uniform
    int a = blockIdx.z;            // 0..2, block-uniform

    const float* wbase;
    if (k < 16)       wbase = W + (((size_t)a * 16 + k) * IN) * 8;
    else if (k == 16) wbase = B + ((size_t)a * IN) * 8;
    else              wbase = RW + ((size_t)a * IN) * 8;
    if (t < IN * 2) w4[t] = ((const float4*)wbase)[t];
    __syncthreads();

    int n0 = blockIdx.x * (BS * 2) + t;
    int n1 = n0 + BS;
    bool v0 = n0 < N, v1 = n1 < N;
    int m0 = v0 ? n0 : 0, m1 = v1 ? n1 : 0;

    float xa[IN], xb[IN];
#pragma unroll
    for (int i = 0; i < IN; i += 4) {
        *(float4*)(xa + i) = *(const float4*)(x + (size_t)m0 * IN + i);
        *(float4*)(xb + i) = *(const float4*)(x + (size_t)m1 * IN + i);
    }

    float r0[8], r1[8];
#pragma unroll
    for (int o = 0; o < 8; o++) { r0[o] = 0.f; r1[o] = 0.f; }

#pragma unroll
    for (int i = 0; i < IN; i++) {
        float4 wA = w4[i * 2];
        float4 wB = w4[i * 2 + 1];
        float x0 = xa[i], x1 = xb[i];
        r0[0] = fmaf(x0, wA.x, r0[0]); r0[1] = fmaf(x0, wA.y, r0[1]);
        r0[2] = fmaf(x0, wA.z, r0[2]); r0[3] = fmaf(x0, wA.w, r0[3]);
        r0[4] = fmaf(x0, wB.x, r0[4]); r0[5] = fmaf(x0, wB.y, r0[5]);
        r0[6] = fmaf(x0, wB.z, r0[6]); r0[7] = fmaf(x0, wB.w, r0[7]);
        r1[0] = fmaf(x1, wA.x, r1[0]); r1[1] = fmaf(x1, wA.y, r1[1]);
        r1[2] = fmaf(x1, wA.z, r1[2]); r1[3] = fmaf(x1, wA.w, r1[3]);
        r1[4] = fmaf(x1, wB.x, r1[4]); r1[5] = fmaf(x1, wB.y, r1[5]);
        r1[6] = fmaf(x1, wB.z, r1[6]); r1[7] = fmaf(x1, wB.w, r1[7]);
    }

    if (k < 17) {
        size_t slab = ((size_t)k * 3 + a) * N;
        if (v0) *(uint4*)(Y + (slab + n0) * 8) = pack8bf(r0);
        if (v1) *(uint4*)(Y + (slab + n1) * 8) = pack8bf(r1);
    } else {
        float rb0 = RB[a * 8 + 0], rb1 = RB[a * 8 + 1], rb2 = RB[a * 8 + 2], rb3 = RB[a * 8 + 3];
        float rb4 = RB[a * 8 + 4], rb5 = RB[a * 8 + 5], rb6 = RB[a * 8 + 6], rb7 = RB[a * 8 + 7];
        if (v0) {
            float* pr = root + ((size_t)a * N + n0) * 8;
            *(float4*)(pr)     = make_float4(r0[0] + rb0, r0[1] + rb1, r0[2] + rb2, r0[3] + rb3);
            *(float4*)(pr + 4) = make_float4(r0[4] + rb4, r0[5] + rb5, r0[6] + rb6, r0[7] + rb7);
        }
        if (v1) {
            float* pr = root + ((size_t)a * N + n1) * 8;
            *(float4*)(pr)     = make_float4(r1[0] + rb0, r1[1] + rb1, r1[2] + rb2, r1[3] + rb3);
            *(float4*)(pr + 4) = make_float4(r1[4] + rb4, r1[5] + rb5, r1[6] + rb6, r1[7] + rb7);
        }
    }
}

// ---- per-(edge, aggregator) msg: src-order compute, [k][a][N][8] Y reads ----
__global__ __launch_bounds__(BS) void msg_kernel(
    const uint2* __restrict__ spq,
    const unsigned short* __restrict__ er_s,   // [E][16] bf16, src-sorted
    const unsigned short* __restrict__ Y,      // [17][3][N][8] bf16
    unsigned short* __restrict__ msg16,        // [E][32] bf16, dst-sorted
    int N, int E)
{
    int tid = blockIdx.x * BS + threadIdx.x;
    int p = tid / 3;
    int j = tid - p * 3;
    if (p >= E) return;

    uint2 sq = spq[p];

    float er[16];
    {
        const uint4* eu = (const uint4*)(er_s + (size_t)p * 16);
        unpack8(eu[0], er);
        unpack8(eu[1], er + 8);
    }

    const unsigned short* yb = Y + ((size_t)j * N + sq.x) * 8;
    size_t kstride = (size_t)3 * N * 8;

    float acc[8];
    unpack8(*(const uint4*)(yb + 16 * kstride), acc);   // bias slot
#pragma unroll
    for (int k = 0; k < 16; k++) {
        float t[8];
        unpack8(*(const uint4*)(yb + (size_t)k * kstride), t);
        float ek = er[k];
#pragma unroll
        for (int o = 0; o < 8; o++) acc[o] = fmaf(ek, t[o], acc[o]);
    }
    unsigned short* mrow = msg16 + (size_t)sq.y * 32;
    *(uint4*)(mrow + j * 8) = pack8bf(acc);
    if (j == 0) *(uint4*)(mrow + 24) = make_uint4(0, 0, 0, 0);  // fill line
}

// ---- wave-per-node gather: 16-row x 64B bf16 tiles, shfl-reduce, add root ----
__global__ __launch_bounds__(BS) void gather_kernel(
    const unsigned short* __restrict__ msg16,  // [E][32] bf16, dst-sorted
    const int* __restrict__ offs,
    const int* __restrict__ degi,
    const float* __restrict__ root,            // [3][N][8] fp32
    float* __restrict__ out, int N)
{
    int n = (blockIdx.x * BS + threadIdx.x) >> 6;   // one wave per node
    if (n >= N) return;
    int lane = threadIdx.x & 63;
    int c = lane & 3;     // uint4-chunk 0..3 (0..2 active)
    int r = lane >> 2;    // row within 16-row tile

    int off = offs[n];
    int d = degi[n];

    float s[8], m[8];
#pragma unroll
    for (int o = 0; o < 8; o++) { s[o] = 0.f; m[o] = -3.402823466e38f; }

    if (c < 3) {
        const unsigned short* base = msg16 + (size_t)off * 32 + c * 8;
        for (int j = r; j < d; j += 16) {
            uint4 v = *(const uint4*)(base + (size_t)j * 32);
            float t[8];
            unpack8(v, t);
#pragma unroll
            for (int o = 0; o < 8; o++) {
                s[o] += t[o];
                m[o] = fmaxf(m[o], t[o]);
            }
        }
    }
#pragma unroll
    for (int mask = 4; mask < 64; mask <<= 1) {
#pragma unroll
        for (int o = 0; o < 8; o++) {
            s[o] += __shfl_xor(s[o], mask);
            m[o] = fmaxf(m[o], __shfl_xor(m[o], mask));
        }
    }
    if (lane >= 3) return;   // lanes 0,1,2 hold aggregator c = lane

    float inv = 1.f / fmaxf((float)d, 1.f);
    const float* pr = root + ((size_t)c * N + n) * 8;
    float4 r0 = *(const float4*)(pr);
    float4 r1 = *(const float4*)(pr + 4);
    float rb[8] = {r0.x, r0.y, r0.z, r0.w, r1.x, r1.y, r1.z, r1.w};
    float rr[8];
#pragma unroll
    for (int o = 0; o < 8; o++) {
        float agg = (c == 0) ? s[o] * inv
                  : (c == 1) ? ((d > 0) ? m[o] : 0.f)
                  : s[o];
        rr[o] = fmaxf(rb[o] + agg, 0.f);
    }
    float* po = out + (size_t)n * 24 + c * 8;
    *(float4*)(po)     = make_float4(rr[0], rr[1], rr[2], rr[3]);
    *(float4*)(po + 4) = make_float4(rr[4], rr[5], rr[6], rr[7]);
}

// ---- output head ----
__global__ void head_kernel(const float* __restrict__ x, const float* __restrict__ W,
                            const float* __restrict__ b, float* __restrict__ out, int N)
{
    int n = blockIdx.x * blockDim.x + threadIdx.x;
    if (n >= N) return;
    float l0 = b[0], l1 = b[1];
#pragma unroll
    for (int i = 0; i < 24; i++) {
        float xi = x[(size_t)n * 24 + i];
        l0 = fmaf(xi, W[i * 2 + 0], l0);
        l1 = fmaf(xi, W[i * 2 + 1], l1);
    }
    out[2 * (size_t)n + 0] = l0;
    out[2 * (size_t)n + 1] = l1;
    float mx = fmaxf(l0, l1);
    float e0 = __expf(l0 - mx), e1 = __expf(l1 - mx);
    float sm = e0 + e1;
    out[2 * (size_t)N + 2 * (size_t)n + 0] = e0 / sm;
    out[2 * (size_t)N + 2 * (size_t)n + 1] = e1 / sm;
}

extern "C" void kernel_launch(void* const* d_in, const int* in_sizes, int n_in,
                              void* d_out, int out_size, void* d_ws, size_t ws_size,
                              hipStream_t stream)
{
    const float* x_feat = (const float*)d_in[0];
    const int*   eidx   = (const int*)d_in[1];
    const float* eattr  = (const float*)d_in[2];
    const float* lpW = (const float*)d_in[3];
    const float* lpb = (const float*)d_in[4];
    const float* tW  = (const float*)d_in[5];
    const float* tb  = (const float*)d_in[6];
    const float* eW1 = (const float*)d_in[7];
    const float* eb1 = (const float*)d_in[8];
    const float* eW2 = (const float*)d_in[9];
    const float* eb2 = (const float*)d_in[10];
    const float* c1W = (const float*)d_in[11];
    const float* c1B = (const float*)d_in[12];
    const float* c1R = (const float*)d_in[13];
    const float* c1b = (const float*)d_in[14];
    const float* c2W = (const float*)d_in[15];
    const float* c2B = (const float*)d_in[16];
    const float* c2R = (const float*)d_in[17];
    const float* c2b = (const float*)d_in[18];
    const float* oW  = (const float*)d_in[19];
    const float* ob  = (const float*)d_in[20];

    int N = in_sizes[0] / 24;
    int E = in_sizes[1] / 2;
    const int* srcA = eidx;
    const int* dstA = eidx + E;

    char* wsb = (char*)d_ws;
    size_t off = 0;
    auto alloc = [&](size_t bytes) {
        off = (off + 255) & ~(size_t)255;
        void* p = wsb + off;
        off += bytes;
        return p;
    };
    unsigned short* Y     = (unsigned short*)alloc((size_t)17 * 3 * N * 8 * 2);
    unsigned short* msg16 = (unsigned short*)alloc((size_t)E * 32 * 2);
    unsigned short* er_s  = (unsigned short*)alloc((size_t)E * 16 * 2);
    float* root = (float*)alloc((size_t)3 * N * 8 * 4);
    float* x16  = (float*)alloc((size_t)N * 16 * 4);
    float* x24a = (float*)alloc((size_t)N * 24 * 4);
    float* x24b = (float*)alloc((size_t)N * 24 * 4);
    int* ibase  = (int*)alloc(((size_t)2 * N + 2) * 4);  // cntS | cntD | cursS | cursD (zeroed)
    int* cntS = ibase;
    int* cntD = ibase + N;
    int* cursS = ibase + 2 * N;
    int* cursD = ibase + 2 * N + 1;
    int* offsS = (int*)alloc((size_t)N * 4);
    int* offsD = (int*)alloc((size_t)N * 4);
    int* jS    = (int*)alloc((size_t)E * 4);
    int* jD    = (int*)alloc((size_t)E * 4);
    uint2* spq = (uint2*)alloc((size_t)E * 8);

    dim3 blk(BS);
    int nb_nodes = (N + BS - 1) / BS;
    int nb_edges = (E + BS - 1) / BS;
    int nb_deg   = (E + BS * 4 - 1) / (BS * 4);
    int nb_msg   = (3 * E + BS - 1) / BS;
    int nb_gath  = ((size_t)N * 64 + BS - 1) / BS;     // one wave per node
    int nb_ypair = (N + BS * 2 - 1) / (BS * 2);        // 2 nodes per thread
    dim3 ygrid(nb_ypair, 18, 3);

    hipMemsetAsync(ibase, 0, (2 * (size_t)N + 2) * 4, stream);

    prep_kernel<<<nb_nodes, blk, 0, stream>>>(x_feat, lpW, lpb, tW, tb, x16, N);

    degjj_kernel<<<nb_deg, blk, 0, stream>>>(srcA, dstA, cntS, cntD, jS, jD, E);
    offsets2_kernel<<<nb_nodes, blk, 0, stream>>>(cntS, cntD, offsS, offsD, cursS, cursD, N);
    er_fill_kernel<<<nb_edges, blk, 0, stream>>>(srcA, dstA, jS, jD, offsS, offsD,
                                                 eattr, eW1, eb1, eW2, eb2, spq, er_s, E);

    // ---- conv1 ----
    ynode_kernel<16><<<ygrid, blk, 0, stream>>>(x16, c1W, c1B, c1R, c1b, Y, root, N);
    msg_kernel<<<nb_msg, blk, 0, stream>>>(spq, er_s, Y, msg16, N, E);
    gather_kernel<<<nb_gath, blk, 0, stream>>>(msg16, offsD, cntD, root, x24a, N);

    // ---- conv2 ----
    ynode_kernel<24><<<ygrid, blk, 0, stream>>>(x24a, c2W, c2B, c2R, c2b, Y, root, N);
    msg_kernel<<<nb_msg, blk, 0, stream>>>(spq, er_s, Y, msg16, N, E);
    gather_kernel<<<nb_gath, blk, 0, stream>>>(msg16, offsD, cntD, root, x24b, N);

    head_kernel<<<nb_nodes, blk, 0, stream>>>(x24b, oW, ob, (float*)d_out, N);
}

// Round 14
// 291.244 us; speedup vs baseline: 1.1042x; 1.1042x over previous
//
#include <hip/hip_runtime.h>

#define BS 256

// ---------------- bf16 helpers ----------------
__device__ __forceinline__ unsigned short f2bf(float f) {
    unsigned x = __float_as_uint(f);
    return (unsigned short)((x + 0x7fffu + ((x >> 16) & 1u)) >> 16);
}
__device__ __forceinline__ void unpack8(uint4 v, float* d) {
    d[0] = __uint_as_float(v.x << 16); d[1] = __uint_as_float(v.x & 0xFFFF0000u);
    d[2] = __uint_as_float(v.y << 16); d[3] = __uint_as_float(v.y & 0xFFFF0000u);
    d[4] = __uint_as_float(v.z << 16); d[5] = __uint_as_float(v.z & 0xFFFF0000u);
    d[6] = __uint_as_float(v.w << 16); d[7] = __uint_as_float(v.w & 0xFFFF0000u);
}
__device__ __forceinline__ uint4 pack8bf(const float* r) {
    unsigned w[4];
#pragma unroll
    for (int j = 0; j < 4; j++)
        w[j] = (unsigned)f2bf(r[2 * j]) | ((unsigned)f2bf(r[2 * j + 1]) << 16);
    return make_uint4(w[0], w[1], w[2], w[3]);
}
// store 24 floats as bf16 into a 64B row (pad last 16B with zeros -> full-line write)
__device__ __forceinline__ void st32bf(unsigned short* p, const float* r) {
    uint4* q = (uint4*)p;
    q[0] = pack8bf(r);
    q[1] = pack8bf(r + 8);
    q[2] = pack8bf(r + 16);
    q[3] = make_uint4(0, 0, 0, 0);
}

// ---- node prep: x16 = relu(relu(x_feat @ lpW + lpb) @ tW + tb) ----
__global__ void prep_kernel(const float* __restrict__ xf,
                            const float* __restrict__ W1, const float* __restrict__ b1,
                            const float* __restrict__ W2, const float* __restrict__ b2,
                            float* __restrict__ x16, int N)
{
    int n = blockIdx.x * blockDim.x + threadIdx.x;
    bool valid = n < N;
    int nn = valid ? n : 0;
    float a[24];
#pragma unroll
    for (int i = 0; i < 24; i += 4)
        *(float4*)(a + i) = *(const float4*)(xf + (size_t)nn * 24 + i);
    float h[32];
#pragma unroll
    for (int j = 0; j < 32; j++) {
        float s = b1[j];
#pragma unroll
        for (int i = 0; i < 24; i++) s = fmaf(a[i], W1[i * 32 + j], s);
        h[j] = fmaxf(s, 0.f);
    }
    if (!valid) return;
#pragma unroll
    for (int j = 0; j < 16; j++) {
        float s = b2[j];
#pragma unroll
        for (int i = 0; i < 32; i++) s = fmaf(h[i], W2[i * 16 + j], s);
        x16[(size_t)n * 16 + j] = fmaxf(s, 0.f);
    }
}

// ---- counting pass: 4 edges/thread, 8 atomics in flight before any wait ----
__global__ void degjj_kernel(const int* __restrict__ srcA, const int* __restrict__ dstA,
                             int* __restrict__ cntS, int* __restrict__ cntD,
                             int* __restrict__ jS, int* __restrict__ jD, int E)
{
    int base = blockIdx.x * (BS * 4) + threadIdx.x;
    int e0 = base, e1 = base + BS, e2 = base + 2 * BS, e3 = base + 3 * BS;
    bool v0 = e0 < E, v1 = e1 < E, v2 = e2 < E, v3 = e3 < E;
    int s0 = 0, s1 = 0, s2 = 0, s3 = 0, d0 = 0, d1 = 0, d2 = 0, d3 = 0;
    if (v0) { s0 = srcA[e0]; d0 = dstA[e0]; }
    if (v1) { s1 = srcA[e1]; d1 = dstA[e1]; }
    if (v2) { s2 = srcA[e2]; d2 = dstA[e2]; }
    if (v3) { s3 = srcA[e3]; d3 = dstA[e3]; }
    int a0 = 0, a1 = 0, a2 = 0, a3 = 0, b0 = 0, b1 = 0, b2 = 0, b3 = 0;
    if (v0) { a0 = atomicAdd(&cntS[s0], 1); b0 = atomicAdd(&cntD[d0], 1); }
    if (v1) { a1 = atomicAdd(&cntS[s1], 1); b1 = atomicAdd(&cntD[d1], 1); }
    if (v2) { a2 = atomicAdd(&cntS[s2], 1); b2 = atomicAdd(&cntD[d2], 1); }
    if (v3) { a3 = atomicAdd(&cntS[s3], 1); b3 = atomicAdd(&cntD[d3], 1); }
    if (v0) { jS[e0] = a0; jD[e0] = b0; }
    if (v1) { jS[e1] = a1; jD[e1] = b1; }
    if (v2) { jS[e2] = a2; jD[e2] = b2; }
    if (v3) { jS[e3] = a3; jD[e3] = b3; }
}

// wave-scan offsets: 1 cursor atomic per wave
__global__ void offsets2_kernel(const int* __restrict__ cntS, const int* __restrict__ cntD,
                                int* __restrict__ offsS, int* __restrict__ offsD,
                                int* __restrict__ cursS, int* __restrict__ cursD, int N)
{
    int n = blockIdx.x * blockDim.x + threadIdx.x;
    int lane = threadIdx.x & 63;
    bool valid = n < N;
    int dS = valid ? cntS[n] : 0;
    int dD = valid ? cntD[n] : 0;
    int sS = dS, sD = dD;
#pragma unroll
    for (int o = 1; o < 64; o <<= 1) {
        int tS = __shfl_up(sS, o);
        int tD = __shfl_up(sD, o);
        if (lane >= o) { sS += tS; sD += tD; }
    }
    int totS = __shfl(sS, 63);
    int totD = __shfl(sD, 63);
    int baseS = 0, baseD = 0;
    if (lane == 63) {
        baseS = atomicAdd(cursS, totS);
        baseD = atomicAdd(cursD, totD);
    }
    baseS = __shfl(baseS, 63);
    baseD = __shfl(baseD, 63);
    if (valid) {
        offsS[n] = baseS + sS - dS;
        offsD[n] = baseD + sD - dD;
    }
}

// ---- fused fill + edge trunk: coalesced eattr, no atomics ----
__global__ __launch_bounds__(BS) void er_fill_kernel(
    const int* __restrict__ srcA, const int* __restrict__ dstA,
    const int* __restrict__ jS, const int* __restrict__ jD,
    const int* __restrict__ offsS, const int* __restrict__ offsD,
    const float* __restrict__ eattr,
    const float* __restrict__ eW1, const float* __restrict__ eb1,
    const float* __restrict__ eW2, const float* __restrict__ eb2,
    uint2* __restrict__ spq, unsigned short* __restrict__ er_s, int E)
{
    int e = blockIdx.x * BS + threadIdx.x;
    if (e >= E) return;
    int s = srcA[e], d = dstA[e];
    int p = offsS[s] + jS[e];
    int q = offsD[d] + jD[e];
    spq[p] = make_uint2((unsigned)s, (unsigned)q);

    float ea[16];
#pragma unroll
    for (int i = 0; i < 16; i += 4)
        *(float4*)(ea + i) = *(const float4*)(eattr + (size_t)e * 16 + i);
    float h[32];
#pragma unroll
    for (int j = 0; j < 32; j++) {
        float t = eb1[j];
#pragma unroll
        for (int i = 0; i < 16; i++) t = fmaf(ea[i], eW1[i * 32 + j], t);
        h[j] = fmaxf(t, 0.f);
    }
    float er[16];
#pragma unroll
    for (int j = 0; j < 16; j++) {
        float t = eb2[j];
#pragma unroll
        for (int i = 0; i < 32; i++) t = fmaf(h[i], eW2[i * 16 + j], t);
        er[j] = 1.f / (1.f + __expf(-t));
    }
    uint4* qo = (uint4*)(er_s + (size_t)p * 16);
    qo[0] = pack8bf(er);
    qo[1] = pack8bf(er + 8);
}

// ---- per-(node-pair, k-slot) Y precompute ----
// Y layout [17][N][32] bf16 (64B padded rows); root [N][24] fp32.
// blockIdx.y = k: 0..15 -> W slot, 16 -> bias slot (x@B), 17 -> root (x@RW+RB).
template <int IN>
__global__ __launch_bounds__(BS) void ynode_kernel(const float* __restrict__ x,
                                                   const float* __restrict__ W,   // [3][16][IN*8]
                                                   const float* __restrict__ B,   // [3][IN*8]
                                                   const float* __restrict__ RW,  // [3][IN][8]
                                                   const float* __restrict__ RB,  // [3][8]
                                                   unsigned short* __restrict__ Y,
                                                   float* __restrict__ root, int N)
{
    __shared__ float4 w4[IN * 6];   // [i][6] float4 = 24 floats per i
    int t = threadIdx.x;
    int k = blockIdx.y;            // 0..17, block-uniform

    for (int idx = t; idx < IN * 6; idx += BS) {
        int i = idx / 6;
        int c = idx - i * 6;
        int a = c >> 1;
        int o = (c & 1) * 4;
        const float* srcp;
        if (k < 16)       srcp = W + (((size_t)a * 16 + k) * IN + i) * 8 + o;
        else if (k == 16) srcp = B + ((size_t)a * IN + i) * 8 + o;
        else              srcp = RW + ((size_t)a * IN + i) * 8 + o;
        w4[idx] = *(const float4*)srcp;
    }
    __syncthreads();

    int n0 = blockIdx.x * (BS * 2) + t;
    int n1 = n0 + BS;
    bool v0 = n0 < N, v1 = n1 < N;
    int m0 = v0 ? n0 : 0, m1 = v1 ? n1 : 0;

    float xa[IN], xb[IN];
#pragma unroll
    for (int i = 0; i < IN; i += 4) {
        *(float4*)(xa + i) = *(const float4*)(x + (size_t)m0 * IN + i);
        *(float4*)(xb + i) = *(const float4*)(x + (size_t)m1 * IN + i);
    }

    float ra[24], rb[24];
#pragma unroll
    for (int j = 0; j < 24; j++) { ra[j] = 0.f; rb[j] = 0.f; }

#pragma unroll
    for (int i = 0; i < IN; i++) {
        float x0 = xa[i], x1 = xb[i];
#pragma unroll
        for (int c = 0; c < 6; c++) {
            float4 w = w4[i * 6 + c];
            ra[c*4+0] = fmaf(x0, w.x, ra[c*4+0]); ra[c*4+1] = fmaf(x0, w.y, ra[c*4+1]);
            ra[c*4+2] = fmaf(x0, w.z, ra[c*4+2]); ra[c*4+3] = fmaf(x0, w.w, ra[c*4+3]);
            rb[c*4+0] = fmaf(x1, w.x, rb[c*4+0]); rb[c*4+1] = fmaf(x1, w.y, rb[c*4+1]);
            rb[c*4+2] = fmaf(x1, w.z, rb[c*4+2]); rb[c*4+3] = fmaf(x1, w.w, rb[c*4+3]);
        }
    }

    if (k < 17) {
        if (v0) st32bf(Y + ((size_t)k * N + n0) * 32, ra);
        if (v1) st32bf(Y + ((size_t)k * N + n1) * 32, rb);
    } else {
        if (v0) {
            float* pr = root + (size_t)n0 * 24;
#pragma unroll
            for (int j = 0; j < 24; j += 4)
                *(float4*)(pr + j) = make_float4(ra[j] + RB[j], ra[j+1] + RB[j+1],
                                                 ra[j+2] + RB[j+2], ra[j+3] + RB[j+3]);
        }
        if (v1) {
            float* pr = root + (size_t)n1 * 24;
#pragma unroll
            for (int j = 0; j < 24; j += 4)
                *(float4*)(pr + j) = make_float4(rb[j] + RB[j], rb[j+1] + RB[j+1],
                                                 rb[j+2] + RB[j+2], rb[j+3] + RB[j+3]);
        }
    }
}

// ---- per-(edge, 8-col part) msg: src-order compute, k-major padded-row Y reads ----
__global__ __launch_bounds__(BS) void msg_kernel(
    const uint2* __restrict__ spq,
    const unsigned short* __restrict__ er_s,   // [E][16] bf16, src-sorted
    const unsigned short* __restrict__ Y,      // [17][N][32] bf16
    unsigned short* __restrict__ msg16,        // [E][32] bf16, dst-sorted
    int N, int E)
{
    int tid = blockIdx.x * BS + threadIdx.x;
    int p = tid / 3;
    int j = tid - p * 3;
    if (p >= E) return;

    uint2 sq = spq[p];

    float er[16];
    {
        const uint4* eu = (const uint4*)(er_s + (size_t)p * 16);
        unpack8(eu[0], er);
        unpack8(eu[1], er + 8);
    }

    const unsigned short* yb = Y + (size_t)sq.x * 32 + j * 8;
    size_t kstride = (size_t)N * 32;

    float acc[8];
    unpack8(*(const uint4*)(yb + 16 * kstride), acc);   // bias slot
#pragma unroll
    for (int k = 0; k < 16; k++) {
        float t[8];
        unpack8(*(const uint4*)(yb + (size_t)k * kstride), t);
        float ek = er[k];
#pragma unroll
        for (int o = 0; o < 8; o++) acc[o] = fmaf(ek, t[o], acc[o]);
    }
    unsigned short* mrow = msg16 + (size_t)sq.y * 32;
    *(uint4*)(mrow + j * 8) = pack8bf(acc);
    if (j == 0) *(uint4*)(mrow + 24) = make_uint4(0, 0, 0, 0);  // fill line
}

// ---- wave-per-node gather: 16-row x 64B bf16 tiles, shfl-reduce, add root ----
__global__ __launch_bounds__(BS) void gather_kernel(
    const unsigned short* __restrict__ msg16,  // [E][32] bf16, dst-sorted
    const int* __restrict__ offs,
    const int* __restrict__ degi,
    const float* __restrict__ root,            // [N][24] fp32
    float* __restrict__ out, int N)
{
    int n = (blockIdx.x * BS + threadIdx.x) >> 6;   // one wave per node
    if (n >= N) return;
    int lane = threadIdx.x & 63;
    int c = lane & 3;     // uint4-chunk 0..3 (0..2 active)
    int r = lane >> 2;    // row within 16-row tile

    int off = offs[n];
    int d = degi[n];

    float s[8], m[8];
#pragma unroll
    for (int o = 0; o < 8; o++) { s[o] = 0.f; m[o] = -3.402823466e38f; }

    if (c < 3) {
        const unsigned short* base = msg16 + (size_t)off * 32 + c * 8;
        for (int j = r; j < d; j += 16) {
            uint4 v = *(const uint4*)(base + (size_t)j * 32);
            float t[8];
            unpack8(v, t);
#pragma unroll
            for (int o = 0; o < 8; o++) {
                s[o] += t[o];
                m[o] = fmaxf(m[o], t[o]);
            }
        }
    }
#pragma unroll
    for (int mask = 4; mask < 64; mask <<= 1) {
#pragma unroll
        for (int o = 0; o < 8; o++) {
            s[o] += __shfl_xor(s[o], mask);
            m[o] = fmaxf(m[o], __shfl_xor(m[o], mask));
        }
    }
    if (lane >= 3) return;   // lanes 0,1,2 hold aggregator c = lane

    float inv = 1.f / fmaxf((float)d, 1.f);
    const float* pr = root + (size_t)n * 24 + c * 8;
    float4 r0 = *(const float4*)(pr);
    float4 r1 = *(const float4*)(pr + 4);
    float rb[8] = {r0.x, r0.y, r0.z, r0.w, r1.x, r1.y, r1.z, r1.w};
    float rr[8];
#pragma unroll
    for (int o = 0; o < 8; o++) {
        float agg = (c == 0) ? s[o] * inv
                  : (c == 1) ? ((d > 0) ? m[o] : 0.f)
                  : s[o];
        rr[o] = fmaxf(rb[o] + agg, 0.f);
    }
    float* po = out + (size_t)n * 24 + c * 8;
    *(float4*)(po)     = make_float4(rr[0], rr[1], rr[2], rr[3]);
    *(float4*)(po + 4) = make_float4(rr[4], rr[5], rr[6], rr[7]);
}

// ---- output head ----
__global__ void head_kernel(const float* __restrict__ x, const float* __restrict__ W,
                            const float* __restrict__ b, float* __restrict__ out, int N)
{
    int n = blockIdx.x * blockDim.x + threadIdx.x;
    if (n >= N) return;
    float l0 = b[0], l1 = b[1];
#pragma unroll
    for (int i = 0; i < 24; i++) {
        float xi = x[(size_t)n * 24 + i];
        l0 = fmaf(xi, W[i * 2 + 0], l0);
        l1 = fmaf(xi, W[i * 2 + 1], l1);
    }
    out[2 * (size_t)n + 0] = l0;
    out[2 * (size_t)n + 1] = l1;
    float mx = fmaxf(l0, l1);
    float e0 = __expf(l0 - mx), e1 = __expf(l1 - mx);
    float sm = e0 + e1;
    out[2 * (size_t)N + 2 * (size_t)n + 0] = e0 / sm;
    out[2 * (size_t)N + 2 * (size_t)n + 1] = e1 / sm;
}

extern "C" void kernel_launch(void* const* d_in, const int* in_sizes, int n_in,
                              void* d_out, int out_size, void* d_ws, size_t ws_size,
                              hipStream_t stream)
{
    const float* x_feat = (const float*)d_in[0];
    const int*   eidx   = (const int*)d_in[1];
    const float* eattr  = (const float*)d_in[2];
    const float* lpW = (const float*)d_in[3];
    const float* lpb = (const float*)d_in[4];
    const float* tW  = (const float*)d_in[5];
    const float* tb  = (const float*)d_in[6];
    const float* eW1 = (const float*)d_in[7];
    const float* eb1 = (const float*)d_in[8];
    const float* eW2 = (const float*)d_in[9];
    const float* eb2 = (const float*)d_in[10];
    const float* c1W = (const float*)d_in[11];
    const float* c1B = (const float*)d_in[12];
    const float* c1R = (const float*)d_in[13];
    const float* c1b = (const float*)d_in[14];
    const float* c2W = (const float*)d_in[15];
    const float* c2B = (const float*)d_in[16];
    const float* c2R = (const float*)d_in[17];
    const float* c2b = (const float*)d_in[18];
    const float* oW  = (const float*)d_in[19];
    const float* ob  = (const float*)d_in[20];

    int N = in_sizes[0] / 24;
    int E = in_sizes[1] / 2;
    const int* srcA = eidx;
    const int* dstA = eidx + E;

    char* wsb = (char*)d_ws;
    size_t off = 0;
    auto alloc = [&](size_t bytes) {
        off = (off + 255) & ~(size_t)255;
        void* p = wsb + off;
        off += bytes;
        return p;
    };
    unsigned short* Y     = (unsigned short*)alloc((size_t)17 * N * 32 * 2);
    unsigned short* msg16 = (unsigned short*)alloc((size_t)E * 32 * 2);
    unsigned short* er_s  = (unsigned short*)alloc((size_t)E * 16 * 2);
    float* root = (float*)alloc((size_t)N * 24 * 4);
    float* x16  = (float*)alloc((size_t)N * 16 * 4);
    float* x24a = (float*)alloc((size_t)N * 24 * 4);
    float* x24b = (float*)alloc((size_t)N * 24 * 4);
    int* ibase  = (int*)alloc(((size_t)2 * N + 2) * 4);  // cntS | cntD | cursS | cursD (zeroed)
    int* cntS = ibase;
    int* cntD = ibase + N;
    int* cursS = ibase + 2 * N;
    int* cursD = ibase + 2 * N + 1;
    int* offsS = (int*)alloc((size_t)N * 4);
    int* offsD = (int*)alloc((size_t)N * 4);
    int* jS    = (int*)alloc((size_t)E * 4);
    int* jD    = (int*)alloc((size_t)E * 4);
    uint2* spq = (uint2*)alloc((size_t)E * 8);

    dim3 blk(BS);
    int nb_nodes = (N + BS - 1) / BS;
    int nb_edges = (E + BS - 1) / BS;
    int nb_deg   = (E + BS * 4 - 1) / (BS * 4);
    int nb_msg   = (3 * E + BS - 1) / BS;
    int nb_gath  = ((size_t)N * 64 + BS - 1) / BS;     // one wave per node
    int nb_ypair = (N + BS * 2 - 1) / (BS * 2);        // 2 nodes per thread
    dim3 ygrid(nb_ypair, 18);

    hipMemsetAsync(ibase, 0, (2 * (size_t)N + 2) * 4, stream);

    prep_kernel<<<nb_nodes, blk, 0, stream>>>(x_feat, lpW, lpb, tW, tb, x16, N);

    degjj_kernel<<<nb_deg, blk, 0, stream>>>(srcA, dstA, cntS, cntD, jS, jD, E);
    offsets2_kernel<<<nb_nodes, blk, 0, stream>>>(cntS, cntD, offsS, offsD, cursS, cursD, N);
    er_fill_kernel<<<nb_edges, blk, 0, stream>>>(srcA, dstA, jS, jD, offsS, offsD,
                                                 eattr, eW1, eb1, eW2, eb2, spq, er_s, E);

    // ---- conv1 ----
    ynode_kernel<16><<<ygrid, blk, 0, stream>>>(x16, c1W, c1B, c1R, c1b, Y, root, N);
    msg_kernel<<<nb_msg, blk, 0, stream>>>(spq, er_s, Y, msg16, N, E);
    gather_kernel<<<nb_gath, blk, 0, stream>>>(msg16, offsD, cntD, root, x24a, N);

    // ---- conv2 ----
    ynode_kernel<24><<<ygrid, blk, 0, stream>>>(x24a, c2W, c2B, c2R, c2b, Y, root, N);
    msg_kernel<<<nb_msg, blk, 0, stream>>>(spq, er_s, Y, msg16, N, E);
    gather_kernel<<<nb_gath, blk, 0, stream>>>(msg16, offsD, cntD, root, x24b, N);

    head_kernel<<<nb_nodes, blk, 0, stream>>>(x24b, oW, ob, (float*)d_out, N);
}

// Round 15
// 284.631 us; speedup vs baseline: 1.1299x; 1.0232x over previous
//
#include <hip/hip_runtime.h>

#define BS 256

// ---------------- bf16 helpers ----------------
__device__ __forceinline__ unsigned short f2bf(float f) {
    unsigned x = __float_as_uint(f);
    return (unsigned short)((x + 0x7fffu + ((x >> 16) & 1u)) >> 16);
}
__device__ __forceinline__ unsigned pack2bf(float a, float b) {
    return (unsigned)f2bf(a) | ((unsigned)f2bf(b) << 16);
}
__device__ __forceinline__ void unpack2(unsigned u, float* d) {
    d[0] = __uint_as_float(u << 16);
    d[1] = __uint_as_float(u & 0xFFFF0000u);
}
__device__ __forceinline__ void unpack8(uint4 v, float* d) {
    unpack2(v.x, d); unpack2(v.y, d + 2); unpack2(v.z, d + 4); unpack2(v.w, d + 6);
}
__device__ __forceinline__ uint4 pack8bf(const float* r) {
    return make_uint4(pack2bf(r[0], r[1]), pack2bf(r[2], r[3]),
                      pack2bf(r[4], r[5]), pack2bf(r[6], r[7]));
}

// ---- node prep: x16 = relu(relu(x_feat @ lpW + lpb) @ tW + tb) ----
__global__ void prep_kernel(const float* __restrict__ xf,
                            const float* __restrict__ W1, const float* __restrict__ b1,
                            const float* __restrict__ W2, const float* __restrict__ b2,
                            float* __restrict__ x16, int N)
{
    int n = blockIdx.x * blockDim.x + threadIdx.x;
    bool valid = n < N;
    int nn = valid ? n : 0;
    float a[24];
#pragma unroll
    for (int i = 0; i < 24; i += 4)
        *(float4*)(a + i) = *(const float4*)(xf + (size_t)nn * 24 + i);
    float h[32];
#pragma unroll
    for (int j = 0; j < 32; j++) {
        float s = b1[j];
#pragma unroll
        for (int i = 0; i < 24; i++) s = fmaf(a[i], W1[i * 32 + j], s);
        h[j] = fmaxf(s, 0.f);
    }
    if (!valid) return;
#pragma unroll
    for (int j = 0; j < 16; j++) {
        float s = b2[j];
#pragma unroll
        for (int i = 0; i < 32; i++) s = fmaf(h[i], W2[i * 16 + j], s);
        x16[(size_t)n * 16 + j] = fmaxf(s, 0.f);
    }
}

// ---- counting pass: 4 edges/thread, 8 atomics in flight before any wait ----
__global__ void degjj_kernel(const int* __restrict__ srcA, const int* __restrict__ dstA,
                             int* __restrict__ cntS, int* __restrict__ cntD,
                             int* __restrict__ jS, int* __restrict__ jD, int E)
{
    int base = blockIdx.x * (BS * 4) + threadIdx.x;
    int e0 = base, e1 = base + BS, e2 = base + 2 * BS, e3 = base + 3 * BS;
    bool v0 = e0 < E, v1 = e1 < E, v2 = e2 < E, v3 = e3 < E;
    int s0 = 0, s1 = 0, s2 = 0, s3 = 0, d0 = 0, d1 = 0, d2 = 0, d3 = 0;
    if (v0) { s0 = srcA[e0]; d0 = dstA[e0]; }
    if (v1) { s1 = srcA[e1]; d1 = dstA[e1]; }
    if (v2) { s2 = srcA[e2]; d2 = dstA[e2]; }
    if (v3) { s3 = srcA[e3]; d3 = dstA[e3]; }
    int a0 = 0, a1 = 0, a2 = 0, a3 = 0, b0 = 0, b1 = 0, b2 = 0, b3 = 0;
    if (v0) { a0 = atomicAdd(&cntS[s0], 1); b0 = atomicAdd(&cntD[d0], 1); }
    if (v1) { a1 = atomicAdd(&cntS[s1], 1); b1 = atomicAdd(&cntD[d1], 1); }
    if (v2) { a2 = atomicAdd(&cntS[s2], 1); b2 = atomicAdd(&cntD[d2], 1); }
    if (v3) { a3 = atomicAdd(&cntS[s3], 1); b3 = atomicAdd(&cntD[d3], 1); }
    if (v0) { jS[e0] = a0; jD[e0] = b0; }
    if (v1) { jS[e1] = a1; jD[e1] = b1; }
    if (v2) { jS[e2] = a2; jD[e2] = b2; }
    if (v3) { jS[e3] = a3; jD[e3] = b3; }
}

// wave-scan offsets: 1 cursor atomic per wave
__global__ void offsets2_kernel(const int* __restrict__ cntS, const int* __restrict__ cntD,
                                int* __restrict__ offsS, int* __restrict__ offsD,
                                int* __restrict__ cursS, int* __restrict__ cursD, int N)
{
    int n = blockIdx.x * blockDim.x + threadIdx.x;
    int lane = threadIdx.x & 63;
    bool valid = n < N;
    int dS = valid ? cntS[n] : 0;
    int dD = valid ? cntD[n] : 0;
    int sS = dS, sD = dD;
#pragma unroll
    for (int o = 1; o < 64; o <<= 1) {
        int tS = __shfl_up(sS, o);
        int tD = __shfl_up(sD, o);
        if (lane >= o) { sS += tS; sD += tD; }
    }
    int totS = __shfl(sS, 63);
    int totD = __shfl(sD, 63);
    int baseS = 0, baseD = 0;
    if (lane == 63) {
        baseS = atomicAdd(cursS, totS);
        baseD = atomicAdd(cursD, totD);
    }
    baseS = __shfl(baseS, 63);
    baseD = __shfl(baseD, 63);
    if (valid) {
        offsS[n] = baseS + sS - dS;
        offsD[n] = baseD + sD - dD;
    }
}

// ---- fused fill + edge trunk: one 64B record per edge {s, q, er[16] bf16, pad} ----
__global__ __launch_bounds__(BS) void er_fill_kernel(
    const int* __restrict__ srcA, const int* __restrict__ dstA,
    const int* __restrict__ jS, const int* __restrict__ jD,
    const int* __restrict__ offsS, const int* __restrict__ offsD,
    const float* __restrict__ eattr,
    const float* __restrict__ eW1, const float* __restrict__ eb1,
    const float* __restrict__ eW2, const float* __restrict__ eb2,
    uint4* __restrict__ erec, int E)
{
    int e = blockIdx.x * BS + threadIdx.x;
    if (e >= E) return;
    int s = srcA[e], d = dstA[e];
    int p = offsS[s] + jS[e];
    int q = offsD[d] + jD[e];

    float ea[16];
#pragma unroll
    for (int i = 0; i < 16; i += 4)
        *(float4*)(ea + i) = *(const float4*)(eattr + (size_t)e * 16 + i);
    float h[32];
#pragma unroll
    for (int j = 0; j < 32; j++) {
        float t = eb1[j];
#pragma unroll
        for (int i = 0; i < 16; i++) t = fmaf(ea[i], eW1[i * 32 + j], t);
        h[j] = fmaxf(t, 0.f);
    }
    float er[16];
#pragma unroll
    for (int j = 0; j < 16; j++) {
        float t = eb2[j];
#pragma unroll
        for (int i = 0; i < 32; i++) t = fmaf(h[i], eW2[i * 16 + j], t);
        er[j] = 1.f / (1.f + __expf(-t));
    }
    unsigned w[8];
#pragma unroll
    for (int j = 0; j < 8; j++) w[j] = pack2bf(er[2 * j], er[2 * j + 1]);
    uint4* rp = erec + (size_t)p * 4;
    rp[0] = make_uint4((unsigned)s, (unsigned)q, w[0], w[1]);
    rp[1] = make_uint4(w[2], w[3], w[4], w[5]);
    rp[2] = make_uint4(w[6], w[7], 0u, 0u);
    rp[3] = make_uint4(0u, 0u, 0u, 0u);   // complete the 64B line
}

// ---- per-(node-pair, k-slot) Y precompute ----
// Y layout [17][N][24] bf16 (48B rows, k-major); root [N][24] fp32.
// LDS-staged output: block writes 512 rows as fully-coalesced uint4 stream.
template <int IN>
__global__ __launch_bounds__(BS) void ynode_kernel(const float* __restrict__ x,
                                                   const float* __restrict__ W,   // [3][16][IN*8]
                                                   const float* __restrict__ B,   // [3][IN*8]
                                                   const float* __restrict__ RW,  // [3][IN][8]
                                                   const float* __restrict__ RB,  // [3][8]
                                                   unsigned short* __restrict__ Y,
                                                   float* __restrict__ root, int N)
{
    __shared__ float4 w4[IN * 6];        // 24 floats per i
    __shared__ unsigned outb[512 * 13];  // 512 rows x 12 u32, pad col -> conflict-free
    int t = threadIdx.x;
    int k = blockIdx.y;                  // 0..17, block-uniform

    for (int idx = t; idx < IN * 6; idx += BS) {
        int i = idx / 6;
        int c = idx - i * 6;
        int a = c >> 1;
        int o = (c & 1) * 4;
        const float* srcp;
        if (k < 16)       srcp = W + (((size_t)a * 16 + k) * IN + i) * 8 + o;
        else if (k == 16) srcp = B + ((size_t)a * IN + i) * 8 + o;
        else              srcp = RW + ((size_t)a * IN + i) * 8 + o;
        w4[idx] = *(const float4*)srcp;
    }
    __syncthreads();

    int nbase = blockIdx.x * (BS * 2);
    int n0 = nbase + t;
    int n1 = n0 + BS;
    bool v0 = n0 < N, v1 = n1 < N;
    int m0 = v0 ? n0 : 0, m1 = v1 ? n1 : 0;

    float xa[IN], xb[IN];
#pragma unroll
    for (int i = 0; i < IN; i += 4) {
        *(float4*)(xa + i) = *(const float4*)(x + (size_t)m0 * IN + i);
        *(float4*)(xb + i) = *(const float4*)(x + (size_t)m1 * IN + i);
    }

    float ra[24], rb[24];
#pragma unroll
    for (int j = 0; j < 24; j++) { ra[j] = 0.f; rb[j] = 0.f; }

#pragma unroll
    for (int i = 0; i < IN; i++) {
        float x0 = xa[i], x1 = xb[i];
#pragma unroll
        for (int c = 0; c < 6; c++) {
            float4 w = w4[i * 6 + c];
            ra[c*4+0] = fmaf(x0, w.x, ra[c*4+0]); ra[c*4+1] = fmaf(x0, w.y, ra[c*4+1]);
            ra[c*4+2] = fmaf(x0, w.z, ra[c*4+2]); ra[c*4+3] = fmaf(x0, w.w, ra[c*4+3]);
            rb[c*4+0] = fmaf(x1, w.x, rb[c*4+0]); rb[c*4+1] = fmaf(x1, w.y, rb[c*4+1]);
            rb[c*4+2] = fmaf(x1, w.z, rb[c*4+2]); rb[c*4+3] = fmaf(x1, w.w, rb[c*4+3]);
        }
    }

    if (k < 17) {
        // stage packed bf16 rows in LDS
#pragma unroll
        for (int j = 0; j < 12; j++) {
            outb[t * 13 + j] = pack2bf(ra[2 * j], ra[2 * j + 1]);
            outb[(t + BS) * 13 + j] = pack2bf(rb[2 * j], rb[2 * j + 1]);
        }
        __syncthreads();
        // stream out: rows are 12 u32 (48B); consecutive uint4 stores
        unsigned* gbase = (unsigned*)(Y + ((size_t)k * N + nbase) * 24);
        int rows = N - nbase; if (rows > 512) rows = 512;
        if (rows == 512) {
#pragma unroll
            for (int v = 0; v < 6; v++) {
                int g = (v * BS + t) * 4;
                uint4 val;
                val.x = outb[((g + 0) / 12) * 13 + (g + 0) % 12];
                val.y = outb[((g + 1) / 12) * 13 + (g + 1) % 12];
                val.z = outb[((g + 2) / 12) * 13 + (g + 2) % 12];
                val.w = outb[((g + 3) / 12) * 13 + (g + 3) % 12];
                *(uint4*)(gbase + g) = val;
            }
        } else {
            int totU = rows * 12;
            for (int g = t; g < totU; g += BS)
                gbase[g] = outb[(g / 12) * 13 + g % 12];
        }
    } else {  // root transform, fp32, direct
        if (v0) {
            float* pr = root + (size_t)n0 * 24;
#pragma unroll
            for (int j = 0; j < 24; j += 4)
                *(float4*)(pr + j) = make_float4(ra[j] + RB[j], ra[j+1] + RB[j+1],
                                                 ra[j+2] + RB[j+2], ra[j+3] + RB[j+3]);
        }
        if (v1) {
            float* pr = root + (size_t)n1 * 24;
#pragma unroll
            for (int j = 0; j < 24; j += 4)
                *(float4*)(pr + j) = make_float4(rb[j] + RB[j], rb[j+1] + RB[j+1],
                                                 rb[j+2] + RB[j+2], rb[j+3] + RB[j+3]);
        }
    }
}

// ---- per-(edge, 8-col part) msg: one 64B record read, k-major 48B-row Y reads ----
__global__ __launch_bounds__(BS) void msg_kernel(
    const uint4* __restrict__ erec,            // [E][4] uint4
    const unsigned short* __restrict__ Y,      // [17][N][24] bf16
    unsigned short* __restrict__ msg16,        // [E][32] bf16, dst-sorted
    int N, int E)
{
    int tid = blockIdx.x * BS + threadIdx.x;
    int p = tid / 3;
    int j = tid - p * 3;
    if (p >= E) return;

    const uint4* rp = erec + (size_t)p * 4;
    uint4 r0 = rp[0];
    uint4 r1 = rp[1];
    uint4 r2 = rp[2];
    unsigned s = r0.x, q = r0.y;

    float er[16];
    unpack2(r0.z, er); unpack2(r0.w, er + 2);
    unpack8(r1, er + 4);
    unpack2(r2.x, er + 12); unpack2(r2.y, er + 14);

    const unsigned short* yb = Y + (size_t)s * 24 + j * 8;
    size_t kstride = (size_t)N * 24;

    float acc[8];
    unpack8(*(const uint4*)(yb + 16 * kstride), acc);   // bias slot
#pragma unroll
    for (int k = 0; k < 16; k++) {
        float t[8];
        unpack8(*(const uint4*)(yb + (size_t)k * kstride), t);
        float ek = er[k];
#pragma unroll
        for (int o = 0; o < 8; o++) acc[o] = fmaf(ek, t[o], acc[o]);
    }
    unsigned short* mrow = msg16 + (size_t)q * 32;
    *(uint4*)(mrow + j * 8) = pack8bf(acc);
    if (j == 0) *(uint4*)(mrow + 24) = make_uint4(0, 0, 0, 0);  // fill line
}

// ---- wave-per-node gather: 16-row x 64B bf16 tiles, shfl-reduce, add root ----
__global__ __launch_bounds__(BS) void gather_kernel(
    const unsigned short* __restrict__ msg16,  // [E][32] bf16, dst-sorted
    const int* __restrict__ offs,
    const int* __restrict__ degi,
    const float* __restrict__ root,            // [N][24] fp32
    float* __restrict__ out, int N)
{
    int n = (blockIdx.x * BS + threadIdx.x) >> 6;   // one wave per node
    if (n >= N) return;
    int lane = threadIdx.x & 63;
    int c = lane & 3;     // uint4-chunk 0..3 (0..2 active)
    int r = lane >> 2;    // row within 16-row tile

    int off = offs[n];
    int d = degi[n];

    float s[8], m[8];
#pragma unroll
    for (int o = 0; o < 8; o++) { s[o] = 0.f; m[o] = -3.402823466e38f; }

    if (c < 3) {
        const unsigned short* base = msg16 + (size_t)off * 32 + c * 8;
        for (int j = r; j < d; j += 16) {
            uint4 v = *(const uint4*)(base + (size_t)j * 32);
            float t[8];
            unpack8(v, t);
#pragma unroll
            for (int o = 0; o < 8; o++) {
                s[o] += t[o];
                m[o] = fmaxf(m[o], t[o]);
            }
        }
    }
#pragma unroll
    for (int mask = 4; mask < 64; mask <<= 1) {
#pragma unroll
        for (int o = 0; o < 8; o++) {
            s[o] += __shfl_xor(s[o], mask);
            m[o] = fmaxf(m[o], __shfl_xor(m[o], mask));
        }
    }
    if (lane >= 3) return;   // lanes 0,1,2 hold aggregator c = lane

    float inv = 1.f / fmaxf((float)d, 1.f);
    const float* pr = root + (size_t)n * 24 + c * 8;
    float4 r0 = *(const float4*)(pr);
    float4 r1 = *(const float4*)(pr + 4);
    float rb[8] = {r0.x, r0.y, r0.z, r0.w, r1.x, r1.y, r1.z, r1.w};
    float rr[8];
#pragma unroll
    for (int o = 0; o < 8; o++) {
        float agg = (c == 0) ? s[o] * inv
                  : (c == 1) ? ((d > 0) ? m[o] : 0.f)
                  : s[o];
        rr[o] = fmaxf(rb[o] + agg, 0.f);
    }
    float* po = out + (size_t)n * 24 + c * 8;
    *(float4*)(po)     = make_float4(rr[0], rr[1], rr[2], rr[3]);
    *(float4*)(po + 4) = make_float4(rr[4], rr[5], rr[6], rr[7]);
}

// ---- output head ----
__global__ void head_kernel(const float* __restrict__ x, const float* __restrict__ W,
                            const float* __restrict__ b, float* __restrict__ out, int N)
{
    int n = blockIdx.x * blockDim.x + threadIdx.x;
    if (n >= N) return;
    float l0 = b[0], l1 = b[1];
#pragma unroll
    for (int i = 0; i < 24; i++) {
        float xi = x[(size_t)n * 24 + i];
        l0 = fmaf(xi, W[i * 2 + 0], l0);
        l1 = fmaf(xi, W[i * 2 + 1], l1);
    }
    out[2 * (size_t)n + 0] = l0;
    out[2 * (size_t)n + 1] = l1;
    float mx = fmaxf(l0, l1);
    float e0 = __expf(l0 - mx), e1 = __expf(l1 - mx);
    float sm = e0 + e1;
    out[2 * (size_t)N + 2 * (size_t)n + 0] = e0 / sm;
    out[2 * (size_t)N + 2 * (size_t)n + 1] = e1 / sm;
}

extern "C" void kernel_launch(void* const* d_in, const int* in_sizes, int n_in,
                              void* d_out, int out_size, void* d_ws, size_t ws_size,
                              hipStream_t stream)
{
    const float* x_feat = (const float*)d_in[0];
    const int*   eidx   = (const int*)d_in[1];
    const float* eattr  = (const float*)d_in[2];
    const float* lpW = (const float*)d_in[3];
    const float* lpb = (const float*)d_in[4];
    const float* tW  = (const float*)d_in[5];
    const float* tb  = (const float*)d_in[6];
    const float* eW1 = (const float*)d_in[7];
    const float* eb1 = (const float*)d_in[8];
    const float* eW2 = (const float*)d_in[9];
    const float* eb2 = (const float*)d_in[10];
    const float* c1W = (const float*)d_in[11];
    const float* c1B = (const float*)d_in[12];
    const float* c1R = (const float*)d_in[13];
    const float* c1b = (const float*)d_in[14];
    const float* c2W = (const float*)d_in[15];
    const float* c2B = (const float*)d_in[16];
    const float* c2R = (const float*)d_in[17];
    const float* c2b = (const float*)d_in[18];
    const float* oW  = (const float*)d_in[19];
    const float* ob  = (const float*)d_in[20];

    int N = in_sizes[0] / 24;
    int E = in_sizes[1] / 2;
    const int* srcA = eidx;
    const int* dstA = eidx + E;

    char* wsb = (char*)d_ws;
    size_t off = 0;
    auto alloc = [&](size_t bytes) {
        off = (off + 255) & ~(size_t)255;
        void* p = wsb + off;
        off += bytes;
        return p;
    };
    unsigned short* Y     = (unsigned short*)alloc((size_t)17 * N * 24 * 2);
    unsigned short* msg16 = (unsigned short*)alloc((size_t)E * 32 * 2);
    uint4* erec = (uint4*)alloc((size_t)E * 64);
    float* root = (float*)alloc((size_t)N * 24 * 4);
    float* x16  = (float*)alloc((size_t)N * 16 * 4);
    float* x24a = (float*)alloc((size_t)N * 24 * 4);
    float* x24b = (float*)alloc((size_t)N * 24 * 4);
    int* ibase  = (int*)alloc(((size_t)2 * N + 2) * 4);  // cntS | cntD | cursS | cursD (zeroed)
    int* cntS = ibase;
    int* cntD = ibase + N;
    int* cursS = ibase + 2 * N;
    int* cursD = ibase + 2 * N + 1;
    int* offsS = (int*)alloc((size_t)N * 4);
    int* offsD = (int*)alloc((size_t)N * 4);
    int* jS    = (int*)alloc((size_t)E * 4);
    int* jD    = (int*)alloc((size_t)E * 4);

    dim3 blk(BS);
    int nb_nodes = (N + BS - 1) / BS;
    int nb_edges = (E + BS - 1) / BS;
    int nb_deg   = (E + BS * 4 - 1) / (BS * 4);
    int nb_msg   = (3 * E + BS - 1) / BS;
    int nb_gath  = ((size_t)N * 64 + BS - 1) / BS;     // one wave per node
    int nb_ypair = (N + BS * 2 - 1) / (BS * 2);        // 2 nodes per thread
    dim3 ygrid(nb_ypair, 18);

    hipMemsetAsync(ibase, 0, (2 * (size_t)N + 2) * 4, stream);

    prep_kernel<<<nb_nodes, blk, 0, stream>>>(x_feat, lpW, lpb, tW, tb, x16, N);

    degjj_kernel<<<nb_deg, blk, 0, stream>>>(srcA, dstA, cntS, cntD, jS, jD, E);
    offsets2_kernel<<<nb_nodes, blk, 0, stream>>>(cntS, cntD, offsS, offsD, cursS, cursD, N);
    er_fill_kernel<<<nb_edges, blk, 0, stream>>>(srcA, dstA, jS, jD, offsS, offsD,
                                                 eattr, eW1, eb1, eW2, eb2, erec, E);

    // ---- conv1 ----
    ynode_kernel<16><<<ygrid, blk, 0, stream>>>(x16, c1W, c1B, c1R, c1b, Y, root, N);
    msg_kernel<<<nb_msg, blk, 0, stream>>>(erec, Y, msg16, N, E);
    gather_kernel<<<nb_gath, blk, 0, stream>>>(msg16, offsD, cntD, root, x24a, N);

    // ---- conv2 ----
    ynode_kernel<24><<<ygrid, blk, 0, stream>>>(x24a, c2W, c2B, c2R, c2b, Y, root, N);
    msg_kernel<<<nb_msg, blk, 0, stream>>>(erec, Y, msg16, N, E);
    gather_kernel<<<nb_gath, blk, 0, stream>>>(msg16, offsD, cntD, root, x24b, N);

    head_kernel<<<nb_nodes, blk, 0, stream>>>(x24b, oW, ob, (float*)d_out, N);
}